// Round 13
// baseline (434.636 us; speedup 1.0000x reference)
//
#include <hip/hip_runtime.h>

// CTC loss forward, B=256 T=2000 L=100 C=36 (S=201, blank=35).
// Round-13: FORWARD/BACKWARD SPLIT. Six structures all landed at ~130 issue
// + ~130 stall cyc/step: one serial chain per wave can't fill its own
// dependency bubbles (VALUBusy 11% == 44% duty on the occupied SIMD).
// Fix is algorithmic: p = sum_s alpha_t[s]*beta_t[s] at any meet t. Run
// alpha forward (t=1..1000) and beta backward (t=1998..1000) INTERLEAVED in
// one wave -- two independent chains, each one's stalls filled by the
// other's issue. Serial depth halves. beta=0 above end kills junk lanes in
// the final product automatically.
//   * both chains FP64, 4 states/lane; renorm every 32 pairs via DPP int-max
//     + exact pow2 exponent strip (shared Eacc)
//   * neighbor exchange: alpha needs lane-1 (wave_shr:1), beta needs lane+1
//     (wave_shl:1)
//   * staging: global_load_lds, 2 rings x 16 slots, 12-pair prefetch,
//     counted WAITV(22) (no memory clobber) + sched_barrier(0)
//   * rolled 32-pair inner loop (fits icache), all ring slots static
// S_Z = sum_t logsumexp(row t) computed in a 2-deep-pipelined f32 prologue.

#define BB    256
#define TT    2000
#define LLAB  100
#define CC    36
#define BLANK 35
#define LN2   0.6931471805599453

typedef __attribute__((address_space(1))) const unsigned int* as1_u32p;
typedef __attribute__((address_space(3))) unsigned int* as3_u32p;

__device__ __forceinline__ void async_row_load(const float* g, float* lds) {
  __builtin_amdgcn_global_load_lds((as1_u32p)(const void*)g,
                                   (as3_u32p)(void*)lds, 4, 0, 0);
}
#define WAITV(n) asm volatile("s_waitcnt vmcnt(" #n ")")
#define SB0 __builtin_amdgcn_sched_barrier(0)

static __device__ __forceinline__ int imax(int a, int b) { return a > b ? a : b; }
static __device__ __forceinline__ int hi32(double x) {
  return (int)(__double_as_longlong(x) >> 32);
}

// lane i <- lane i-1 (lane 0 gets 0): DPP wave_shr:1
static __device__ __forceinline__ double dpp_up1(double x) {
  long long v = __double_as_longlong(x);
  int lo = (int)(unsigned int)(v & 0xFFFFFFFFLL);
  int hi = (int)(v >> 32);
  int slo = __builtin_amdgcn_update_dpp(0, lo, 0x138, 0xF, 0xF, true);
  int shi = __builtin_amdgcn_update_dpp(0, hi, 0x138, 0xF, 0xF, true);
  return __longlong_as_double(((long long)shi << 32) | (unsigned int)slo);
}
// lane i <- lane i+1 (lane 63 gets 0): DPP wave_shl:1
static __device__ __forceinline__ double dpp_dn1(double x) {
  long long v = __double_as_longlong(x);
  int lo = (int)(unsigned int)(v & 0xFFFFFFFFLL);
  int hi = (int)(v >> 32);
  int slo = __builtin_amdgcn_update_dpp(0, lo, 0x130, 0xF, 0xF, true);
  int shi = __builtin_amdgcn_update_dpp(0, hi, 0x130, 0xF, 0xF, true);
  return __longlong_as_double(((long long)shi << 32) | (unsigned int)slo);
}
// wave-wide int max via DPP, broadcast from lane 63.
static __device__ __forceinline__ int wave_imax(int x) {
  x = imax(x, __builtin_amdgcn_update_dpp(x, x, 0x111, 0xF, 0xF, false));
  x = imax(x, __builtin_amdgcn_update_dpp(x, x, 0x112, 0xF, 0xF, false));
  x = imax(x, __builtin_amdgcn_update_dpp(x, x, 0x114, 0xF, 0xF, false));
  x = imax(x, __builtin_amdgcn_update_dpp(x, x, 0x118, 0xF, 0xF, false));
  x = imax(x, __builtin_amdgcn_update_dpp(x, x, 0x142, 0xA, 0xF, false));
  x = imax(x, __builtin_amdgcn_update_dpp(x, x, 0x143, 0xC, 0xF, false));
  return __builtin_amdgcn_readlane(x, 63);
}

__global__ __launch_bounds__(64) void ctc_fused(
    const float* __restrict__ logits,
    const int*   __restrict__ input_labels,
    const int*   __restrict__ input_len,
    const int*   __restrict__ label_len,
    float*       __restrict__ out)
{
  __shared__ float ringF[16][CC];    // fwd rows, slot = row & 15
  __shared__ float ringB[16][CC];    // bwd rows, slot = row & 15
  const int b    = blockIdx.x;
  const int lane = threadIdx.x;
  const float* lg = logits + (size_t)b * TT * CC;
  const int ilen = input_len[b];
  const int llen = label_len[b];

  // ---------------- prologue: S_Z, 2-deep pipelined -----------------------
  float sz = 0.f;
  {
    float4 qa[9];
    const float4* r0 = (const float4*)(lg + (size_t)lane * CC);
#pragma unroll
    for (int i = 0; i < 9; ++i) qa[i] = r0[i];
    for (int t = lane; t < TT; t += 64) {
      int tn = t + 64;
      const float4* rn =
          (const float4*)(lg + (size_t)((tn < TT) ? tn : t) * CC);
      float4 qb[9];
#pragma unroll
      for (int i = 0; i < 9; ++i) qb[i] = rn[i];     // overlap next-row loads
      float m = qa[0].x;
#pragma unroll
      for (int i = 0; i < 9; ++i) {
        m = fmaxf(m, qa[i].x); m = fmaxf(m, qa[i].y);
        m = fmaxf(m, qa[i].z); m = fmaxf(m, qa[i].w);
      }
      float s = 0.f;
#pragma unroll
      for (int i = 0; i < 9; ++i) {
        s += __expf(qa[i].x - m) + __expf(qa[i].y - m)
           + __expf(qa[i].z - m) + __expf(qa[i].w - m);
      }
      float z = m + __logf(s);
      if (t == 0 || t < ilen) sz += z;
#pragma unroll
      for (int i = 0; i < 9; ++i) qa[i] = qb[i];
    }
  }
#pragma unroll
  for (int o = 32; o; o >>= 1) sz += __shfl_xor(sz, o, 64);
  const float S_Z = sz;

  // ---------------- per-lane static state (states 4l..4l+3) ---------------
  const int* lb = input_labels + b * LLAB;
  const int i0 = 2 * lane, i1 = 2 * lane + 1, im = 2 * lane - 1, ix = 2 * lane + 2;
  const int c1  = (i0 < LLAB) ? lb[i0] : 0;           // ext[4l+1]
  const int c3  = (i1 < LLAB) ? lb[i1] : 0;           // ext[4l+3]
  const int cm  = (im >= 0 && im < LLAB) ? lb[im] : 0;
  const int cnx = (ix < LLAB) ? lb[ix] : 0;           // ext[4l+5] (next lane c1)
  const double sk1d  = ((lane >= 1) && (c1 != BLANK) && (c1 != cm)) ? 1.0 : 0.0;
  const double sk3d  = (c3 != c1) ? 1.0 : 0.0;        // labels never == blank
  const double skB1d = (c3 != c1) ? 1.0 : 0.0;        // skip into 4l+3
  const double skB3d = (cnx != c3) ? 1.0 : 0.0;       // skip into 4l+5
  const int cb = BLANK, cc1 = c1, cc3 = c3, ccx = cnx;

  // ---------------- alpha_0 and beta_1999 init -----------------------------
  double a0 = 0.0, a1 = 0.0, a2 = 0.0, a3 = 0.0;
  {
    float eb = lg[BLANK];
    float e1 = lg[c1];
    if (lane == 0) { a0 = (double)__expf(eb); a1 = (double)__expf(e1); }
  }
  const int sb  = 4 * lane;
  const int end = 2 * llen;
  const int ep  = (end > 0) ? (end - 1) : 0;
  // beta init = indicator(end) + indicator(ep)  (handles llen==0 -> 2 at s=0)
  double b0 = (double)((sb + 0 == end) + (sb + 0 == ep));
  double b1 = (double)((sb + 1 == end) + (sb + 1 == ep));
  double b2 = (double)((sb + 2 == end) + (sb + 2 == ep));
  double b3 = (double)((sb + 3 == end) + (sb + 3 == ep));
  const int pth = 2000 - ((ilen < TT) ? ilen : TT);   // bwd applies iff p > pth

  // drain everything; from here vmcnt counts ONLY ring loads
  asm volatile("s_waitcnt vmcnt(0) lgkmcnt(0)" ::: "memory");

  // pre-issue pairs 1..12: fwd rows 1..12, bwd rows 1999..1988 (2/pair)
  const float* pfF = lg + (size_t)1 * CC;
  const float* pfB = lg + (size_t)1999 * CC;
#pragma unroll
  for (int k = 1; k <= 12; ++k) {
    if (lane < CC) {
      async_row_load(pfF + lane, &ringF[k & 15][0]);
      async_row_load(pfB + lane, &ringB[(2000 - k) & 15][0]);
    }
    pfF += CC; pfB -= CC;
  }
  // pfF -> row 13, pfB -> row 1987 (pair 1 issues these)

  // preamble: pair-1 e-rows (fwd row 1 slot 1, bwd row 1999 slot 15)
  double pvF0, pvF1, pvF3, EB0, EB1, EB3, EBX;
  WAITV(22);                       // retired >= 2 -> pair-1 rows resident
  SB0;
  pvF0 = (double)__expf(ringF[1][cb]);
  pvF1 = (double)__expf(ringF[1][cc1]);
  pvF3 = (double)__expf(ringF[1][cc3]);
  EB0  = (double)__expf(ringB[15][cb]);
  EB1  = (double)__expf(ringB[15][cc1]);
  EB3  = (double)__expf(ringB[15][cc3]);
  EBX  = (double)__expf(ringB[15][ccx]);

  double n3 = 0.0, n3k = 0.0;            // alpha_0 has a3 == 0 everywhere
  double nb0 = dpp_dn1(b0), nb1 = dpp_dn1(b1);
  int Eacc = 0;
  int p = 1;

  // pair p: fwd body t=p (emission row p), bwd body beta_{1999-p} from
  // beta_{2000-p} (emission row 2000-p). Reads pair p+1's e-rows; issues
  // pair p+12's rows. All ring slots static via J (p === J+1 mod 16).
#define PSTEP(J, DO_BWD)                                                   \
  {                                                                        \
    if (lane < CC) {                                                       \
      async_row_load(pfF + lane, &ringF[((J) + 13) & 15][0]);              \
      async_row_load(pfB + lane, &ringB[(3 - (J)) & 15][0]);               \
    }                                                                      \
    pfF += CC; pfB -= CC;                                                  \
    WAITV(22);                                                             \
    SB0;                                                                   \
    const float* rf_ = &ringF[((J) + 2) & 15][0];                          \
    float nfb = rf_[cb], nf1 = rf_[cc1], nf3 = rf_[cc3];                   \
    const float* rb_ = &ringB[(14 - (J)) & 15][0];                         \
    float ngb = rb_[cb], ng1 = rb_[cc1], ng3 = rb_[cc3], ngx = rb_[ccx];   \
    if (p < ilen) {                                                        \
      double u0 = (a0 + n3) * pvF0;                                        \
      double u1 = (a1 + a0 + n3k) * pvF1;                                  \
      double u2 = (a2 + a1) * pvF0;       /* pv2 == pv0 (blank) */         \
      double u3 = (a3 + a2 + a1 * sk3d) * pvF3;                            \
      a0 = u0; a1 = u1; a2 = u2; a3 = u3;                                  \
    }                                                                      \
    if ((DO_BWD) && p > pth) {                                             \
      double tB1 = EB1 * b1, tB2 = EB0 * b2, tB3 = EB3 * b3;               \
      double v0 = EB0 * b0 + tB1;                                          \
      double v1 = tB1 + tB2 + tB3 * skB1d;                                 \
      double v2 = tB2 + tB3;                                               \
      double v3 = tB3 + EB0 * nb0 + (EBX * nb1) * skB3d;                   \
      b0 = v0; b1 = v1; b2 = v2; b3 = v3;                                  \
    }                                                                      \
    n3 = dpp_up1(a3); n3k = n3 * sk1d;                                     \
    if (DO_BWD) { nb0 = dpp_dn1(b0); nb1 = dpp_dn1(b1); }                  \
    pvF0 = (double)__expf(nfb); pvF1 = (double)__expf(nf1);                \
    pvF3 = (double)__expf(nf3);                                            \
    EB0 = (double)__expf(ngb); EB1 = (double)__expf(ng1);                  \
    EB3 = (double)__expf(ng3); EBX = (double)__expf(ngx);                  \
    ++p;                                                                   \
  }

#define RENORM2                                                            \
  {                                                                        \
    int hA = imax(imax(hi32(a0), hi32(a1)), imax(hi32(a2), hi32(a3)));     \
    int eA = wave_imax(hA) >> 20;                                          \
    Eacc += eA - 1023;                                                     \
    double sA = __longlong_as_double((long long)(2046 - eA) << 52);        \
    a0 *= sA; a1 *= sA; a2 *= sA; a3 *= sA; n3 *= sA; n3k *= sA;           \
    int hB = imax(imax(hi32(b0), hi32(b1)), imax(hi32(b2), hi32(b3)));     \
    int eB = wave_imax(hB) >> 20;                                          \
    Eacc += eB - 1023;                                                     \
    double sB = __longlong_as_double((long long)(2046 - eB) << 52);        \
    b0 *= sB; b1 *= sB; b2 *= sB; b3 *= sB; nb0 *= sB; nb1 *= sB;          \
  }

  // 31 blocks of 32 pairs (p = 1..992), rolled outer loop (icache-friendly)
#pragma unroll 1
  for (int blk = 0; blk < 31; ++blk) {
#pragma unroll
    for (int j = 0; j < 32; ++j) { PSTEP(j, true) }
    RENORM2
  }
  // tail: pairs 993..999 full, pair 1000 fwd-only (beta_1000 must survive)
#pragma unroll
  for (int j = 0; j < 7; ++j) { PSTEP(j, true) }
  { PSTEP(7, false) }

  // drain outstanding ring loads before teardown
  asm volatile("s_waitcnt vmcnt(0)" ::: "memory");

  // ---------------- combine: p = sum_s alpha_1000[s] * beta_1000[s] -------
  double contrib = a0 * b0 + a1 * b1 + a2 * b2 + a3 * b3;
#pragma unroll
  for (int o = 32; o; o >>= 1) contrib += __shfl_xor(contrib, o, 64);

  if (lane == 0) {
    long long u = __double_as_longlong(contrib);
    int e = (int)((u >> 52) & 0x7FF) - 1023;
    double mant = __longlong_as_double(
        (u & 0xFFFFFFFFFFFFFULL) | 0x3FF0000000000000ULL);
    double lc = (double)e * LN2 + (double)__logf((float)mant);
    double loss = -(lc + (double)Eacc * LN2 - (double)S_Z);
    out[b] = (float)loss;
  }
#undef PSTEP
#undef RENORM2
}

extern "C" void kernel_launch(void* const* d_in, const int* in_sizes, int n_in,
                              void* d_out, int out_size, void* d_ws, size_t ws_size,
                              hipStream_t stream) {
  const float* logits = (const float*)d_in[0];
  const int* labels   = (const int*)d_in[1];
  const int* ilen     = (const int*)d_in[2];
  const int* llen     = (const int*)d_in[3];
  float* out          = (float*)d_out;
  (void)in_sizes; (void)n_in; (void)out_size; (void)d_ws; (void)ws_size;
  hipLaunchKernelGGL(ctc_fused, dim3(BB), dim3(64), 0, stream,
                     logits, labels, ilen, llen, out);
}

// Round 14
// 121.115 us; speedup vs baseline: 3.5886x; 3.5886x over previous
//
#include <hip/hip_runtime.h>

// CTC loss forward, B=256 T=2000 L=100 C=36 (S=201, blank=35).
// Round-14: fwd/bwd split ACROSS TWO WAVES (R13's interleave-in-one-wave
// serialized both chains behind shared fences -> 2x regression; the split
// itself is verified correct, absmax=0). Block = 128 threads:
//   wave 0: alpha forward,  bodies t = 1..999   (meet at t* = 999)
//   wave 1: beta  backward, bodies r = 1999..1000 (beta_999 from beta_1999)
// Waves run on different SIMDs of one CU -- true parallel chains, no shared
// fences. Each wave uses R11's structure (best measured: 260 cyc/body):
// FP64 state, 4 states/lane, two 16-row register batches prefetched ahead
// + sched_barrier(0), DPP neighbor exchange, renorm every 32 bodies via
// DPP int-max + exact pow2 exponent strip. Combine via LDS + syncthreads:
// p = sum_s alpha_999[s] * beta_999[s]. S_Z prologue split across waves.

#define BB    256
#define TT    2000
#define LLAB  100
#define CC    36
#define BLANK 35
#define LN2   0.6931471805599453

#define SB0 __builtin_amdgcn_sched_barrier(0)

static __device__ __forceinline__ int imax(int a, int b) { return a > b ? a : b; }
static __device__ __forceinline__ int hi32(double x) {
  return (int)(__double_as_longlong(x) >> 32);
}

// lane i <- lane i-1 (lane 0 gets 0): DPP wave_shr:1   [HW-verified R4..R13]
static __device__ __forceinline__ double dpp_up1(double x) {
  long long v = __double_as_longlong(x);
  int lo = (int)(unsigned int)(v & 0xFFFFFFFFLL);
  int hi = (int)(v >> 32);
  int slo = __builtin_amdgcn_update_dpp(0, lo, 0x138, 0xF, 0xF, true);
  int shi = __builtin_amdgcn_update_dpp(0, hi, 0x138, 0xF, 0xF, true);
  return __longlong_as_double(((long long)shi << 32) | (unsigned int)slo);
}
// lane i <- lane i+1 (lane 63 gets 0): DPP wave_shl:1   [HW-verified R13]
static __device__ __forceinline__ double dpp_dn1(double x) {
  long long v = __double_as_longlong(x);
  int lo = (int)(unsigned int)(v & 0xFFFFFFFFLL);
  int hi = (int)(v >> 32);
  int slo = __builtin_amdgcn_update_dpp(0, lo, 0x130, 0xF, 0xF, true);
  int shi = __builtin_amdgcn_update_dpp(0, hi, 0x130, 0xF, 0xF, true);
  return __longlong_as_double(((long long)shi << 32) | (unsigned int)slo);
}
// wave-wide int max via DPP, broadcast from lane 63.
static __device__ __forceinline__ int wave_imax(int x) {
  x = imax(x, __builtin_amdgcn_update_dpp(x, x, 0x111, 0xF, 0xF, false));
  x = imax(x, __builtin_amdgcn_update_dpp(x, x, 0x112, 0xF, 0xF, false));
  x = imax(x, __builtin_amdgcn_update_dpp(x, x, 0x114, 0xF, 0xF, false));
  x = imax(x, __builtin_amdgcn_update_dpp(x, x, 0x118, 0xF, 0xF, false));
  x = imax(x, __builtin_amdgcn_update_dpp(x, x, 0x142, 0xA, 0xF, false));
  x = imax(x, __builtin_amdgcn_update_dpp(x, x, 0x143, 0xC, 0xF, false));
  return __builtin_amdgcn_readlane(x, 63);
}

__global__ __launch_bounds__(128, 1) void ctc_fused(
    const float* __restrict__ logits,
    const int*   __restrict__ input_labels,
    const int*   __restrict__ input_len,
    const int*   __restrict__ label_len,
    float*       __restrict__ out)
{
  __shared__ double bsh[64][4];      // beta_999 from wave 1
  __shared__ float  szsh;            // wave 1's S_Z partial
  __shared__ int    eaccsh;          // wave 1's Eacc
  const int b    = blockIdx.x;
  const int tid  = threadIdx.x;
  const int wave = tid >> 6;
  const int lane = tid & 63;
  const float* lg = logits + (size_t)b * TT * CC;
  const int ilen = input_len[b];
  const int llen = label_len[b];

  // ---------------- prologue: S_Z partial over this wave's half -----------
  float sz = 0.f;
  for (int t = wave * 1000 + lane; t < wave * 1000 + 1000; t += 64) {
    const float4* r4 = (const float4*)(lg + (size_t)t * CC);
    float4 q[9];
#pragma unroll
    for (int i = 0; i < 9; ++i) q[i] = r4[i];
    float m = q[0].x;
#pragma unroll
    for (int i = 0; i < 9; ++i) {
      m = fmaxf(m, q[i].x); m = fmaxf(m, q[i].y);
      m = fmaxf(m, q[i].z); m = fmaxf(m, q[i].w);
    }
    float s = 0.f;
#pragma unroll
    for (int i = 0; i < 9; ++i) {
      s += __expf(q[i].x - m) + __expf(q[i].y - m)
         + __expf(q[i].z - m) + __expf(q[i].w - m);
    }
    float z = m + __logf(s);
    if (t == 0 || t < ilen) sz += z;
  }
#pragma unroll
  for (int o = 32; o; o >>= 1) sz += __shfl_xor(sz, o, 64);

  // ---------------- per-lane static label state ---------------------------
  const int* lb = input_labels + b * LLAB;
  const int i0 = 2 * lane, i1 = 2 * lane + 1, im = 2 * lane - 1, ix = 2 * lane + 2;
  const int c1  = (i0 < LLAB) ? lb[i0] : 0;
  const int c3  = (i1 < LLAB) ? lb[i1] : 0;
  const int cm  = (im >= 0 && im < LLAB) ? lb[im] : 0;
  const int cnx = (ix < LLAB) ? lb[ix] : 0;
  const double sk1d  = ((lane >= 1) && (c1 != BLANK) && (c1 != cm)) ? 1.0 : 0.0;
  const double sk3d  = (c3 != c1) ? 1.0 : 0.0;
  const double skB1d = (c3 != c1) ? 1.0 : 0.0;
  const double skB3d = (cnx != c3) ? 1.0 : 0.0;
  const int cb = BLANK;

  if (wave == 0) {
    // ================= WAVE 0: alpha forward, bodies t=1..999 =============
    double a0 = 0.0, a1 = 0.0, a2 = 0.0, a3 = 0.0;
    {
      float eb = lg[BLANK], e1 = lg[c1];
      if (lane == 0) { a0 = (double)__expf(eb); a1 = (double)__expf(e1); }
    }
    double pv0, pv1, pv3;
    {
      const float* rp = lg + CC;                 // row 1
      pv0 = (double)__expf(rp[cb]);
      pv1 = (double)__expf(rp[c1]);
      pv3 = (double)__expf(rp[c3]);
    }
    float Ab[16], A1[16], A3[16], Bb[16], B1[16], B3[16];
#pragma unroll
    for (int k = 0; k < 16; ++k) {               // A = rows 2..17
      const float* rp = lg + (size_t)(2 + k) * CC;
      Ab[k] = rp[cb]; A1[k] = rp[c1]; A3[k] = rp[c3];
    }
    SB0;
    double n3 = 0.0, n3k = 0.0;
    int EaccA = 0;
    const int aEnd = (ilen < 1000) ? ilen : 1000;   // bodies t < aEnd update

#define ABODY(T, Qb, Q1, Q3)                                               \
    {                                                                      \
      double q0 = (double)__expf(Qb);                                      \
      double q1 = (double)__expf(Q1);                                      \
      double q3 = (double)__expf(Q3);                                      \
      if ((T) < aEnd) {                                                    \
        double u0 = (a0 + n3) * pv0;                                       \
        double u1 = (a1 + a0 + n3k) * pv1;                                 \
        double u2 = (a2 + a1) * pv0;                                       \
        double u3 = (a3 + a2 + a1 * sk3d) * pv3;                           \
        a0 = u0; a1 = u1; a2 = u2; a3 = u3;                                \
      }                                                                    \
      n3 = dpp_up1(a3); n3k = n3 * sk1d;                                   \
      pv0 = q0; pv1 = q1; pv3 = q3;                                        \
    }

    // 32 blocks of 32 bodies: t = 1..1024 (t>=1000 are no-ops; loads <=1041)
#pragma unroll 1
    for (int t0 = 1; t0 <= 993; t0 += 32) {
#pragma unroll
      for (int k = 0; k < 16; ++k) {             // B = rows t0+17..t0+32
        const float* rp = lg + (size_t)(t0 + 17 + k) * CC;
        Bb[k] = rp[cb]; B1[k] = rp[c1]; B3[k] = rp[c3];
      }
      SB0;
#pragma unroll
      for (int j = 0; j < 16; ++j) { const int t = t0 + j; ABODY(t, Ab[j], A1[j], A3[j]) }
#pragma unroll
      for (int k = 0; k < 16; ++k) {             // next A = rows t0+33..t0+48
        const float* rp = lg + (size_t)(t0 + 33 + k) * CC;
        Ab[k] = rp[cb]; A1[k] = rp[c1]; A3[k] = rp[c3];
      }
      SB0;
#pragma unroll
      for (int j = 0; j < 16; ++j) { const int t = t0 + 16 + j; ABODY(t, Bb[j], B1[j], B3[j]) }
      {
        int h = imax(imax(hi32(a0), hi32(a1)), imax(hi32(a2), hi32(a3)));
        int e = wave_imax(h) >> 20;
        EaccA += e - 1023;
        double s = __longlong_as_double((long long)(2046 - e) << 52);
        a0 *= s; a1 *= s; a2 *= s; a3 *= s; n3 *= s; n3k *= s;
      }
    }
#undef ABODY

    __syncthreads();                             // beta published to LDS

    // combine: p = sum_s alpha_999[s] * beta_999[s]
    double contrib = a0 * bsh[lane][0] + a1 * bsh[lane][1]
                   + a2 * bsh[lane][2] + a3 * bsh[lane][3];
#pragma unroll
    for (int o = 32; o; o >>= 1) contrib += __shfl_xor(contrib, o, 64);

    if (lane == 0) {
      long long u = __double_as_longlong(contrib);
      int e = (int)((u >> 52) & 0x7FF) - 1023;
      double mant = __longlong_as_double(
          (u & 0xFFFFFFFFFFFFFULL) | 0x3FF0000000000000ULL);
      double lc = (double)e * LN2 + (double)__logf((float)mant);
      double loss = -(lc + (double)(EaccA + eaccsh) * LN2
                      - (double)(sz + szsh));
      out[b] = (float)loss;
    }
  } else {
    // ================= WAVE 1: beta backward, bodies r=1999..1000 =========
    const int sb  = 4 * lane;
    const int end = 2 * llen;
    const int ep  = (end > 0) ? (end - 1) : 0;
    double b0 = (double)((sb + 0 == end) + (sb + 0 == ep));
    double b1 = (double)((sb + 1 == end) + (sb + 1 == ep));
    double b2 = (double)((sb + 2 == end) + (sb + 2 == ep));
    double b3 = (double)((sb + 3 == end) + (sb + 3 == ep));
    double EB0, EB1, EB3, EBX;
    {
      const float* rp = lg + (size_t)1999 * CC;
      EB0 = (double)__expf(rp[cb]);
      EB1 = (double)__expf(rp[c1]);
      EB3 = (double)__expf(rp[c3]);
      EBX = (double)__expf(rp[cnx]);
    }
    float Ab[16], A1[16], A3[16], AX[16], Bb[16], B1[16], B3[16], BX[16];
#pragma unroll
    for (int k = 0; k < 16; ++k) {               // A = rows 1998..1983
      const float* rp = lg + (size_t)(1998 - k) * CC;
      Ab[k] = rp[cb]; A1[k] = rp[c1]; A3[k] = rp[c3]; AX[k] = rp[cnx];
    }
    SB0;
    double nb0 = dpp_dn1(b0), nb1 = dpp_dn1(b1);
    int EaccB = 0;

#define BBODY(R, Qb, Q1, Q3, Qx)                                           \
    {                                                                      \
      double q0 = (double)__expf(Qb);                                      \
      double q1 = (double)__expf(Q1);                                      \
      double q3 = (double)__expf(Q3);                                      \
      double qx = (double)__expf(Qx);                                      \
      if ((R) >= 1000 && (R) < ilen) {                                     \
        double tB1 = EB1 * b1, tB2 = EB0 * b2, tB3 = EB3 * b3;             \
        double v0 = EB0 * b0 + tB1;                                        \
        double v1 = tB1 + tB2 + tB3 * skB1d;                               \
        double v2 = tB2 + tB3;                                             \
        double v3 = tB3 + EB0 * nb0 + (EBX * nb1) * skB3d;                 \
        b0 = v0; b1 = v1; b2 = v2; b3 = v3;                                \
      }                                                                    \
      nb0 = dpp_dn1(b0); nb1 = dpp_dn1(b1);                                \
      EB0 = q0; EB1 = q1; EB3 = q3; EBX = qx;                              \
    }

    // 32 blocks of 32 bodies: r = 1999..976 (r<1000 no-ops; loads >= 959)
#pragma unroll 1
    for (int r0 = 1999; r0 >= 1007; r0 -= 32) {
#pragma unroll
      for (int k = 0; k < 16; ++k) {             // B = rows r0-17-k
        const float* rp = lg + (size_t)(r0 - 17 - k) * CC;
        Bb[k] = rp[cb]; B1[k] = rp[c1]; B3[k] = rp[c3]; BX[k] = rp[cnx];
      }
      SB0;
#pragma unroll
      for (int j = 0; j < 16; ++j) { const int r = r0 - j; BBODY(r, Ab[j], A1[j], A3[j], AX[j]) }
#pragma unroll
      for (int k = 0; k < 16; ++k) {             // next A = rows r0-33-k
        const float* rp = lg + (size_t)(r0 - 33 - k) * CC;
        Ab[k] = rp[cb]; A1[k] = rp[c1]; A3[k] = rp[c3]; AX[k] = rp[cnx];
      }
      SB0;
#pragma unroll
      for (int j = 0; j < 16; ++j) { const int r = r0 - 16 - j; BBODY(r, Bb[j], B1[j], B3[j], BX[j]) }
      {
        int h = imax(imax(hi32(b0), hi32(b1)), imax(hi32(b2), hi32(b3)));
        int e = wave_imax(h) >> 20;
        EaccB += e - 1023;
        double s = __longlong_as_double((long long)(2046 - e) << 52);
        b0 *= s; b1 *= s; b2 *= s; b3 *= s; nb0 *= s; nb1 *= s;
      }
    }
#undef BBODY

    bsh[lane][0] = b0; bsh[lane][1] = b1;
    bsh[lane][2] = b2; bsh[lane][3] = b3;
    if (lane == 0) { szsh = sz; eaccsh = EaccB; }
    __syncthreads();                             // publish to wave 0
  }
}

extern "C" void kernel_launch(void* const* d_in, const int* in_sizes, int n_in,
                              void* d_out, int out_size, void* d_ws, size_t ws_size,
                              hipStream_t stream) {
  const float* logits = (const float*)d_in[0];
  const int* labels   = (const int*)d_in[1];
  const int* ilen     = (const int*)d_in[2];
  const int* llen     = (const int*)d_in[3];
  float* out          = (float*)d_out;
  (void)in_sizes; (void)n_in; (void)out_size; (void)d_ws; (void)ws_size;
  hipLaunchKernelGGL(ctc_fused, dim3(BB), dim3(128), 0, stream,
                     logits, labels, ilen, llen, out);
}